// Round 7
// baseline (39.547 us; speedup 1.0000x reference)
//
#include <hip/hip_runtime.h>

// out[b, m] = sum_n exp(-0.5 * ||inputs[b,n] - stars[m]||^2)
// B=32, N=4096, M=1024, D=3, fp32 in/out.
//
// exp(-0.5*d2) = E_n * 2^(Sx*x + Sy*y + Sz*z + K), E_n = 2^(-C2*||x||^2).
// R6 post-mortem: the ~19us gap over the ~8.5us issue floor is STALLS
// (4 waves/SIMD, LDS latency on critical path, syncthreads), not issue count.
// This round: register-broadcast structure.
//   - each lane loads ONE point (coalesced, once), computes E in-register
//   - hot loop broadcasts point j via v_readlane (uniform j -> SGPR),
//     inner math = scalar v_fma with one SGPR operand per instr
//   - NO LDS, NO syncthreads, NO loads in the hot loop
//   - ~34 VGPR -> __launch_bounds__(256,8), grid=2048 blocks = 8 waves/SIMD
// Per (point, star): 3 fma + 1 v_exp_f32 + 1 fma. Broadcast: 4 readlane/point.

#define NB 32
#define NN 4096
#define NM 1024
#define NCHUNK 64               // blocks per batch along N
#define NPB (NN / NCHUNK)       // 64 points per block (one per lane)
#define TPB 256                 // threads per block (4 waves)
#define MPT (NM / TPB)          // 4 stars per thread

__device__ __forceinline__ float exp2_hw(float x) {
    float r;
    asm("v_exp_f32 %0, %1" : "=v"(r) : "v"(x));
    return r;
}

// Broadcast lane j's value to all lanes (uniform j -> v_readlane_b32 -> SGPR).
__device__ __forceinline__ float bcast(float v, int j) {
    return __int_as_float(__builtin_amdgcn_readlane(__float_as_int(v), j));
}

__global__ __launch_bounds__(TPB, 8) void gau_part(const float* __restrict__ inputs,
                                                   const float* __restrict__ stars,
                                                   float* __restrict__ part) {
    constexpr float C2  = 0.72134752044448169f;  // 0.5*log2(e)
    constexpr float L2E = 1.44269504088896340f;  // log2(e)

    const int b     = blockIdx.x / NCHUNK;
    const int chunk = blockIdx.x % NCHUNK;
    const int t     = threadIdx.x;
    const int lane  = t & 63;

    // Per-thread star constants (scalar; ~16 VGPR + 4 acc)
    float Sx[MPT], Sy[MPT], Sz[MPT], K[MPT], acc[MPT];
#pragma unroll
    for (int k = 0; k < MPT; ++k) {
        int m = t + k * TPB;
        float sx = stars[3 * m + 0];
        float sy = stars[3 * m + 1];
        float sz = stars[3 * m + 2];
        Sx[k] = L2E * sx;
        Sy[k] = L2E * sy;
        Sz[k] = L2E * sz;
        K[k]  = -C2 * (sx * sx + sy * sy + sz * sz);
        acc[k] = 0.0f;
    }

    // Each lane owns one point of this block's 64-point chunk (every wave
    // loads the same 64 points; L2 absorbs the 4x redundancy).
    const float* p = inputs + ((size_t)b * NN + (size_t)chunk * NPB + lane) * 3;
    float px = p[0], py = p[1], pz = p[2];
    float pE = exp2_hw(-C2 * px * px - C2 * py * py - C2 * pz * pz);

    // Hot loop: broadcast point j from registers; no memory ops at all.
#pragma unroll 8
    for (int j = 0; j < 64; ++j) {
        float x = bcast(px, j);
        float y = bcast(py, j);
        float z = bcast(pz, j);
        float E = bcast(pE, j);
#pragma unroll
        for (int k = 0; k < MPT; ++k) {
            float u = fmaf(z, Sz[k], K[k]);
            u = fmaf(y, Sy[k], u);
            u = fmaf(x, Sx[k], u);
            acc[k] = fmaf(E, exp2_hw(u), acc[k]);
        }
    }

    // Coalesced partial store: part[(b*NCHUNK + chunk)*NM + m]
    float* pb = part + ((size_t)b * NCHUNK + chunk) * NM;
#pragma unroll
    for (int k = 0; k < MPT; ++k) {
        pb[t + k * TPB] = acc[k];
    }
}

__global__ __launch_bounds__(256) void gau_reduce(const float* __restrict__ part,
                                                  float* __restrict__ out) {
    const int o = blockIdx.x * 256 + threadIdx.x;  // o = b*NM + m, 32K total
    const int b = o >> 10;
    const int m = o & (NM - 1);
    const float* pb = part + (size_t)b * NCHUNK * NM + m;
    float s = 0.0f;
#pragma unroll
    for (int c = 0; c < NCHUNK; ++c) {
        s += pb[(size_t)c * NM];  // adjacent lanes -> adjacent m: coalesced
    }
    out[o] = s;
}

extern "C" void kernel_launch(void* const* d_in, const int* in_sizes, int n_in,
                              void* d_out, int out_size, void* d_ws, size_t ws_size,
                              hipStream_t stream) {
    const float* inputs = (const float*)d_in[0];  // (32, 4096, 3)
    const float* stars  = (const float*)d_in[1];  // (1024, 3)
    float* out  = (float*)d_out;                  // (32, 1024)
    float* part = (float*)d_ws;                   // (32*64, 1024) = 8 MB

    gau_part<<<NB * NCHUNK, TPB, 0, stream>>>(inputs, stars, part);
    gau_reduce<<<(NB * NM) / 256, 256, 0, stream>>>(part, out);
}

// Round 8
// 32.753 us; speedup vs baseline: 1.2074x; 1.2074x over previous
//
#include <hip/hip_runtime.h>

// out[b, m] = sum_n exp(-0.5 * ||inputs[b,n] - stars[m]||^2)
// B=32, N=4096, M=1024, D=3, fp32 in/out.
//
// exp(-0.5*d2) = E_n * 2^(Sx*x + Sy*y + Sz*z + K), E_n = 2^(-C2*||x||^2).
// R7 post-mortem: structure ranking: LDS-broadcast (27.3) < atomics (28.3)
//   < uniform-global (34.1) < readlane (39.5). Dual-pipe floor ~7us; R5 gap
//   is stalls at 4 waves/SIMD with a 4-deep dependent chain per term.
// This round: R5's LDS-broadcast structure at 8 waves/SIMD:
//   - NCHUNK=64 -> 2048 blocks, launch_bounds(256,8)
//   - scalar fma inner loop (pk_fma is half-rate/element: same cycles,
//     fewer VGPRs -> ~40 VGPR, fits 8 waves/SIMD)
//   - LDS float4 (x,y,z,E) per point, uniform broadcast reads
// Per (point, star): 3 fma + 1 v_exp_f32 + 1 acc-fma.

#define NB 32
#define NN 4096
#define NM 1024
#define NCHUNK 64               // blocks per batch along N
#define NPB (NN / NCHUNK)       // 64 points per block
#define TPB 256                 // threads per block (4 waves)
#define MPT (NM / TPB)          // 4 stars per thread

__device__ __forceinline__ float exp2_hw(float x) {
    float r;
    asm("v_exp_f32 %0, %1" : "=v"(r) : "v"(x));
    return r;
}

__global__ __launch_bounds__(TPB, 8) void gau_part(const float* __restrict__ inputs,
                                                   const float* __restrict__ stars,
                                                   float* __restrict__ part) {
    constexpr float C2  = 0.72134752044448169f;  // 0.5*log2(e)
    constexpr float L2E = 1.44269504088896340f;  // log2(e)

    const int b     = blockIdx.x / NCHUNK;
    const int chunk = blockIdx.x % NCHUNK;
    const int t     = threadIdx.x;

    __shared__ float4 pts[NPB];  // (x, y, z, E)

    if (t < NPB) {
        const float* p = inputs + ((size_t)b * NN + (size_t)chunk * NPB + t) * 3;
        float x = p[0], y = p[1], z = p[2];
        float q = -C2 * x * x - C2 * y * y - C2 * z * z;
        pts[t] = make_float4(x, y, z, exp2_hw(q));
    }

    // Per-thread star constants (scalar -> ~16 VGPR + 4 acc)
    float Sx[MPT], Sy[MPT], Sz[MPT], K[MPT], acc[MPT];
#pragma unroll
    for (int k = 0; k < MPT; ++k) {
        int m = t + k * TPB;
        float sx = stars[3 * m + 0];
        float sy = stars[3 * m + 1];
        float sz = stars[3 * m + 2];
        Sx[k] = L2E * sx;
        Sy[k] = L2E * sy;
        Sz[k] = L2E * sz;
        K[k]  = -C2 * (sx * sx + sy * sy + sz * sz);
        acc[k] = 0.0f;
    }

    __syncthreads();

#pragma unroll 8
    for (int i = 0; i < NPB; ++i) {
        float4 p = pts[i];  // uniform address -> LDS broadcast, conflict-free
#pragma unroll
        for (int k = 0; k < MPT; ++k) {
            float u = fmaf(p.z, Sz[k], K[k]);
            u = fmaf(p.y, Sy[k], u);
            u = fmaf(p.x, Sx[k], u);
            acc[k] = fmaf(p.w, exp2_hw(u), acc[k]);
        }
    }

    // Coalesced partial store: part[(b*NCHUNK + chunk)*NM + m]
    float* pb = part + ((size_t)b * NCHUNK + chunk) * NM;
#pragma unroll
    for (int k = 0; k < MPT; ++k) {
        pb[t + k * TPB] = acc[k];
    }
}

__global__ __launch_bounds__(256) void gau_reduce(const float* __restrict__ part,
                                                  float* __restrict__ out) {
    const int o = blockIdx.x * 256 + threadIdx.x;  // o = b*NM + m, 32K total
    const int b = o >> 10;
    const int m = o & (NM - 1);
    const float* pb = part + (size_t)b * NCHUNK * NM + m;
    float s = 0.0f;
#pragma unroll
    for (int c = 0; c < NCHUNK; ++c) {
        s += pb[(size_t)c * NM];  // adjacent lanes -> adjacent m: coalesced
    }
    out[o] = s;
}

extern "C" void kernel_launch(void* const* d_in, const int* in_sizes, int n_in,
                              void* d_out, int out_size, void* d_ws, size_t ws_size,
                              hipStream_t stream) {
    const float* inputs = (const float*)d_in[0];  // (32, 4096, 3)
    const float* stars  = (const float*)d_in[1];  // (1024, 3)
    float* out  = (float*)d_out;                  // (32, 1024)
    float* part = (float*)d_ws;                   // (32*64, 1024) = 8 MB

    gau_part<<<NB * NCHUNK, TPB, 0, stream>>>(inputs, stars, part);
    gau_reduce<<<(NB * NM) / 256, 256, 0, stream>>>(part, out);
}